// Round 4
// baseline (395.601 us; speedup 1.0000x reference)
//
#include <hip/hip_runtime.h>
#include <hip/hip_bf16.h>

#define BB 4
#define KK 4
#define DD 192
#define NN 16
#define RR 6
#define LL 4096
#define NC 64
#define CL 64
#define C38 38

__device__ __forceinline__ float ex2(float x) {
#if __has_builtin(__builtin_amdgcn_exp2f)
  return __builtin_amdgcn_exp2f(x);
#else
  return exp2f(x);
#endif
}

// t index for column i of a tile, per direction
__device__ __forceinline__ int tmap(int k, int tile, int i) {
  if (k == 0 || k == 2) return tile * 64 + i;
  if (k == 1) return i * 64 + tile;
  return 4095 - (i * 64 + tile);
}

// ---------------- K1: projection + scan-order staging ----------------
__global__ __launch_bounds__(256) void k_proj(
    const float* __restrict__ x, const float* __restrict__ y,
    const float* __restrict__ xpw, const float* __restrict__ dpw,
    const float* __restrict__ dpb,
    float* __restrict__ delta_ws, float* __restrict__ u_ws,
    float* __restrict__ bs_ws, float* __restrict__ cs_ws)
{
  __shared__ float xlds[DD * 65];   // [d][65] for x/y tile; reused as delta [i][193]
  __shared__ float xd[40 * 65];     // [c][65] x_dbl tile
  const int bid = blockIdx.x;
  const int tile = bid & 63;
  const int k = (bid >> 6) & 3;
  const int b = bid >> 8;
  const int tid = threadIdx.x;
  const int ti = tid & 63;
  const int ds4 = tid >> 6;

  // lane's spatial load index (contiguous across lanes for ALL directions)
  const int m = (k == 2) ? (4095 - tile * 64 - ti) : (tile * 64 + ti);

  const float* xb = x + (size_t)b * DD * LL;
  for (int d0 = 0; d0 < DD; d0 += 4) {
    int d = d0 + ds4;
    xlds[d * 65 + ti] = xb[(size_t)d * LL + m];
  }
  __syncthreads();

  // x_dbl: wave wv computes channels c0..c0+9
  const int wv = __builtin_amdgcn_readfirstlane(ds4);
  const int c0 = wv * 10;
  float acc[10];
#pragma unroll
  for (int j = 0; j < 10; ++j) acc[j] = 0.f;
  const float* Wk = xpw + (size_t)k * C38 * DD;
#pragma unroll 4
  for (int d = 0; d < DD; ++d) {
    float xv = xlds[d * 65 + ti];
#pragma unroll
    for (int j = 0; j < 10; ++j) {
      int c = c0 + j; c = c < C38 ? c : C38 - 1;
      acc[j] = fmaf(xv, Wk[c * DD + d], acc[j]);
    }
  }
#pragma unroll
  for (int j = 0; j < 10; ++j) {
    int c = c0 + j;
    if (c < C38) xd[c * 65 + ti] = acc[j];
  }
  __syncthreads();

  // delta = softplus(dt_proj + bias); stage into xlds as [i][193]
  const float* dpwk = dpw + (size_t)k * DD * RR;
  const float* dpbk = dpb + (size_t)k * DD;
  for (int j = 0; j < 48; ++j) {
    int d = wv * 48 + j;
    float s = dpbk[d];
#pragma unroll
    for (int r = 0; r < RR; ++r) s = fmaf(xd[r * 65 + ti], dpwk[d * RR + r], s);
    float dl = (s > 20.f) ? s : log1pf(__expf(s));
    xlds[ti * 193 + d] = dl;
  }
  __syncthreads();

  const size_t bkL = (size_t)(b * KK + k) * LL;
  for (int idx = tid; idx < 64 * DD; idx += 256) {
    int i = idx / DD, d = idx - i * DD;
    int tg = tmap(k, tile, i);
    delta_ws[(bkL + tg) * DD + d] = xlds[i * 193 + d];
  }
  __syncthreads();

  // y tile -> u_ws (same traversal)
  const float* yb = y + (size_t)b * DD * LL;
  for (int d0 = 0; d0 < DD; d0 += 4) {
    int d = d0 + ds4;
    xlds[d * 65 + ti] = yb[(size_t)d * LL + m];
  }
  __syncthreads();
  for (int idx = tid; idx < 64 * DD; idx += 256) {
    int i = idx / DD, d = idx - i * DD;
    int tg = tmap(k, tile, i);
    u_ws[(bkL + tg) * DD + d] = xlds[d * 65 + i];
  }
  // B, C channels
  for (int idx = tid; idx < 64 * NN; idx += 256) {
    int i = idx >> 4, n = idx & 15;
    int tg = tmap(k, tile, i);
    bs_ws[(bkL + tg) * NN + n] = xd[(RR + n) * 65 + i];
    cs_ws[(bkL + tg) * NN + n] = xd[(RR + NN + n) * 65 + i];
  }
}

// ---------------- K2: pass 1 — per-chunk (P, s) ----------------
__global__ __launch_bounds__(192) void k_scan1(
    const float* __restrict__ delta_ws, const float* __restrict__ u_ws,
    const float* __restrict__ bs_ws, const float* __restrict__ A_logs,
    float* __restrict__ cP, float* __restrict__ cS)
{
  __shared__ float Bl[CL * NN];
  const int bid = blockIdx.x;
  const int c = bid & (NC - 1);
  const int bk = bid >> 6;
  const int k = bk & 3;
  const int d = threadIdx.x;
  if (c == NC - 1) return;  // last chunk's state is never consumed
  const int t0 = c * CL;

  float A2[NN];
  const float* al = A_logs + (size_t)(k * DD + d) * NN;
#pragma unroll
  for (int n = 0; n < NN; ++n) A2[n] = -__expf(al[n]) * 1.4426950408889634f;

  const float* bsrc = bs_ws + ((size_t)bk * LL + t0) * NN;
  for (int i = threadIdx.x; i < CL * NN; i += 192) Bl[i] = bsrc[i];
  __syncthreads();

  const float* dptr = delta_ws + ((size_t)bk * LL + t0) * DD + d;
  const float* uptr = u_ws + ((size_t)bk * LL + t0) * DD + d;
  float h[NN];
#pragma unroll
  for (int n = 0; n < NN; ++n) h[n] = 0.f;
  float dsum = 0.f;
  for (int t = 0; t < CL; ++t) {
    float delta = dptr[t * DD];
    float u = uptr[t * DD];
    float du = delta * u;
    dsum += delta;
    const float4* bq = (const float4*)(Bl + t * NN);
    float4 b0 = bq[0], b1 = bq[1], b2 = bq[2], b3 = bq[3];
    float bb[16] = {b0.x,b0.y,b0.z,b0.w, b1.x,b1.y,b1.z,b1.w,
                    b2.x,b2.y,b2.z,b2.w, b3.x,b3.y,b3.z,b3.w};
#pragma unroll
    for (int n = 0; n < NN; ++n)
      h[n] = fmaf(ex2(delta * A2[n]), h[n], du * bb[n]);
  }
  float* pp = cP + (((size_t)bk * NC + c) * DD + d) * NN;
  float* sp = cS + (((size_t)bk * NC + c) * DD + d) * NN;
#pragma unroll
  for (int n = 0; n < NN; ++n) { pp[n] = ex2(dsum * A2[n]); sp[n] = h[n]; }
}

// ---------------- K3: pass 2 — compose h_in, rescan with y ----------------
__global__ __launch_bounds__(192) void k_scan2(
    float* __restrict__ dy_ws,   // delta in, y out (in-place)
    const float* __restrict__ u_ws,
    const float* __restrict__ bs_ws, const float* __restrict__ cs_ws,
    const float* __restrict__ A_logs, const float* __restrict__ Ds,
    const float* __restrict__ cP, const float* __restrict__ cS)
{
  __shared__ float Bl[CL * NN];
  __shared__ float Cl2[CL * NN];
  const int bid = blockIdx.x;
  const int c = bid & (NC - 1);
  const int bk = bid >> 6;
  const int k = bk & 3;
  const int d = threadIdx.x;
  const int t0 = c * CL;

  float A2[NN];
  const float* al = A_logs + (size_t)(k * DD + d) * NN;
#pragma unroll
  for (int n = 0; n < NN; ++n) A2[n] = -__expf(al[n]) * 1.4426950408889634f;
  const float Dkd = Ds[k * DD + d];

  // compose h_in from previous chunks' (P, s)
  float h[NN];
#pragma unroll
  for (int n = 0; n < NN; ++n) h[n] = 0.f;
  for (int j = 0; j < c; ++j) {
    const float4* pq = (const float4*)(cP + (((size_t)bk * NC + j) * DD + d) * NN);
    const float4* sq = (const float4*)(cS + (((size_t)bk * NC + j) * DD + d) * NN);
    float4 p0 = pq[0], p1 = pq[1], p2 = pq[2], p3 = pq[3];
    float4 s0 = sq[0], s1 = sq[1], s2 = sq[2], s3 = sq[3];
    float pp[16] = {p0.x,p0.y,p0.z,p0.w, p1.x,p1.y,p1.z,p1.w,
                    p2.x,p2.y,p2.z,p2.w, p3.x,p3.y,p3.z,p3.w};
    float ss[16] = {s0.x,s0.y,s0.z,s0.w, s1.x,s1.y,s1.z,s1.w,
                    s2.x,s2.y,s2.z,s2.w, s3.x,s3.y,s3.z,s3.w};
#pragma unroll
    for (int n = 0; n < NN; ++n) h[n] = fmaf(pp[n], h[n], ss[n]);
  }

  const float* bsrc = bs_ws + ((size_t)bk * LL + t0) * NN;
  const float* csrc = cs_ws + ((size_t)bk * LL + t0) * NN;
  for (int i = threadIdx.x; i < CL * NN; i += 192) {
    Bl[i] = bsrc[i];
    Cl2[i] = csrc[i];
  }
  __syncthreads();

  float* dyp = dy_ws + ((size_t)bk * LL + t0) * DD + d;
  const float* uptr = u_ws + ((size_t)bk * LL + t0) * DD + d;
  for (int t = 0; t < CL; ++t) {
    float delta = dyp[t * DD];
    float u = uptr[t * DD];
    float du = delta * u;
    const float4* bq = (const float4*)(Bl + t * NN);
    const float4* cq = (const float4*)(Cl2 + t * NN);
    float4 b0 = bq[0], b1 = bq[1], b2 = bq[2], b3 = bq[3];
    float4 c0 = cq[0], c1 = cq[1], c2 = cq[2], c3 = cq[3];
    float bb[16] = {b0.x,b0.y,b0.z,b0.w, b1.x,b1.y,b1.z,b1.w,
                    b2.x,b2.y,b2.z,b2.w, b3.x,b3.y,b3.z,b3.w};
    float cc[16] = {c0.x,c0.y,c0.z,c0.w, c1.x,c1.y,c1.z,c1.w,
                    c2.x,c2.y,c2.z,c2.w, c3.x,c3.y,c3.z,c3.w};
    float yv = 0.f;
#pragma unroll
    for (int n = 0; n < NN; ++n) {
      h[n] = fmaf(ex2(delta * A2[n]), h[n], du * bb[n]);
      yv = fmaf(h[n], cc[n], yv);
    }
    dyp[t * DD] = fmaf(Dkd, u, yv);  // + Ds*u fused, overwrite delta slot
  }
}

// ---------------- K4: direction merge + LayerNorm ----------------
__global__ __launch_bounds__(256) void k_comb(
    const float* __restrict__ ybuf, const float* __restrict__ gamma,
    const float* __restrict__ beta, float* __restrict__ out)
{
  const int lane = threadIdx.x & 63;
  const int gl = blockIdx.x * 4 + (threadIdx.x >> 6);  // 0..B*L-1
  const int b = gl >> 12;
  const int l = gl & 4095;
  const int hh = l >> 6, ww = l & 63;
  const int lt = ww * 64 + hh;
  const size_t base = (size_t)b * KK * LL * DD;
  const float* y0 = ybuf + base + (size_t)(0 * LL + l) * DD;
  const float* y1 = ybuf + base + (size_t)(1 * LL + lt) * DD;
  const float* y2 = ybuf + base + (size_t)(2 * LL + (4095 - l)) * DD;
  const float* y3 = ybuf + base + (size_t)(3 * LL + (4095 - lt)) * DD;

  float s[3];
  float sum = 0.f, sq = 0.f;
#pragma unroll
  for (int j = 0; j < 3; ++j) {
    int d = lane + j * 64;
    float v = y0[d] + y1[d] + y2[d] + y3[d];
    s[j] = v; sum += v; sq = fmaf(v, v, sq);
  }
#pragma unroll
  for (int o = 1; o < 64; o <<= 1) {
    sum += __shfl_xor(sum, o, 64);
    sq  += __shfl_xor(sq, o, 64);
  }
  const float mu = sum * (1.f / 192.f);
  const float var = sq * (1.f / 192.f) - mu * mu;
  const float inv = rsqrtf(var + 1e-5f);
  float* op = out + (size_t)gl * DD;
#pragma unroll
  for (int j = 0; j < 3; ++j) {
    int d = lane + j * 64;
    op[d] = (s[j] - mu) * inv * gamma[d] + beta[d];
  }
}

extern "C" void kernel_launch(void* const* d_in, const int* in_sizes, int n_in,
                              void* d_out, int out_size, void* d_ws, size_t ws_size,
                              hipStream_t stream) {
  const float* x     = (const float*)d_in[0];
  const float* y     = (const float*)d_in[1];
  const float* xpw   = (const float*)d_in[2];
  const float* dpw   = (const float*)d_in[3];
  const float* dpb   = (const float*)d_in[4];
  const float* alogs = (const float*)d_in[5];
  const float* ds    = (const float*)d_in[6];
  const float* gamma = (const float*)d_in[7];
  const float* beta  = (const float*)d_in[8];
  float* w = (float*)d_ws;

  float* delta = w;                  // 12,582,912 floats (also y_out, also K4 input)
  float* u     = w + 12582912;       // 12,582,912
  float* bs    = w + 25165824;       //  1,048,576
  float* cs    = w + 26214400;       //  1,048,576
  float* cP    = w + 27262976;       //  3,145,728
  float* cS    = w + 30408704;       //  3,145,728  -> total 33,554,432 floats = 128 MiB

  k_proj<<<1024, 256, 0, stream>>>(x, y, xpw, dpw, dpb, delta, u, bs, cs);
  k_scan1<<<1024, 192, 0, stream>>>(delta, u, bs, alogs, cP, cS);
  k_scan2<<<1024, 192, 0, stream>>>(delta, u, bs, cs, alogs, ds, cP, cS);
  k_comb<<<4096, 256, 0, stream>>>(delta, gamma, beta, (float*)d_out);
}

// Round 5
// 255.565 us; speedup vs baseline: 1.5479x; 1.5479x over previous
//
#include <hip/hip_runtime.h>
#include <hip/hip_bf16.h>

#define BB 4
#define KK 4
#define DD 192
#define NN 16
#define RR 6
#define LL 4096
#define NC 64
#define CL 64
#define C38 38

__device__ __forceinline__ float ex2(float x) {
#if __has_builtin(__builtin_amdgcn_exp2f)
  return __builtin_amdgcn_exp2f(x);
#else
  return exp2f(x);
#endif
}

// t index for column i of a tile, per direction
__device__ __forceinline__ int tmap(int k, int tile, int i) {
  if (k == 0 || k == 2) return tile * 64 + i;
  if (k == 1) return i * 64 + tile;
  return 4095 - (i * 64 + tile);
}

// ---------------- K1: projection + scan-order staging ----------------
// LDS 26.5 KB -> 5-6 blocks/CU (vs 60 KB / 2 blocks before).
__global__ __launch_bounds__(256) void k_proj(
    const float* __restrict__ x, const float* __restrict__ y,
    const float* __restrict__ xpw, const float* __restrict__ dpw,
    const float* __restrict__ dpb,
    float* __restrict__ delta_ws, float* __restrict__ u_ws,
    float* __restrict__ bs_ws, float* __restrict__ cs_ws)
{
  __shared__ float xs[64 * 65];    // 16.6 KB chunk staging [r][65]
  __shared__ float xd[38 * 65];    //  9.9 KB x_dbl [c][65]
  const int bid = blockIdx.x;
  const int tile = bid & 63;
  const int k = (bid >> 6) & 3;
  const int b = bid >> 8;
  const int tid = threadIdx.x;
  const int ti = tid & 63;
  const int ds4 = tid >> 6;
  const int wv = __builtin_amdgcn_readfirstlane(ds4);

  // lane's spatial load index (contiguous across lanes for ALL directions)
  const int m = (k == 2) ? (4095 - tile * 64 - ti) : (tile * 64 + ti);
  const int tg = tmap(k, tile, ti);
  const size_t bkL = (size_t)(b * KK + k) * LL;

  // ---- einsum x_dbl: wave wv computes 10 channels starting c0 (wave3: 28..37, overlap ok)
  const int c0 = (wv == 3) ? 28 : wv * 10;
  const float* Wk = xpw + (size_t)k * C38 * DD;
  const float* xb = x + (size_t)b * DD * LL;
  float acc[10];
#pragma unroll
  for (int j = 0; j < 10; ++j) acc[j] = 0.f;

  for (int ch = 0; ch < 3; ++ch) {
    for (int r = ds4; r < 64; r += 4)
      xs[r * 65 + ti] = xb[(size_t)(ch * 64 + r) * LL + m];
    __syncthreads();
    const float* Wc = Wk + ch * 64;
#pragma unroll 8
    for (int dj = 0; dj < 64; ++dj) {
      float xv = xs[dj * 65 + ti];
#pragma unroll
      for (int j = 0; j < 10; ++j)
        acc[j] = fmaf(xv, Wc[(c0 + j) * DD + dj], acc[j]);
    }
    __syncthreads();
  }
#pragma unroll
  for (int j = 0; j < 10; ++j) xd[(c0 + j) * 65 + ti] = acc[j];
  __syncthreads();

  // ---- delta = softplus(dt_proj + bias), DIRECT store (48 consecutive d per thread)
  const float* dpwk = dpw + (size_t)k * DD * RR + (size_t)(wv * 48) * RR;
  const float* dpbk = dpb + (size_t)k * DD + wv * 48;
  float* dst = delta_ws + (bkL + tg) * DD + wv * 48;
  for (int j0 = 0; j0 < 48; j0 += 4) {
    float4 v;
    float* vp = (float*)&v;
#pragma unroll
    for (int q = 0; q < 4; ++q) {
      int jj = j0 + q;
      float s = dpbk[jj];
#pragma unroll
      for (int r = 0; r < RR; ++r)
        s = fmaf(xd[r * 65 + ti], dpwk[jj * RR + r], s);
      vp[q] = (s > 20.f) ? s : __logf(1.f + __expf(s));
    }
    *(float4*)(dst + j0) = v;
  }

  // ---- B, C channels
  for (int idx = tid; idx < 64 * NN; idx += 256) {
    int i = idx >> 4, n = idx & 15;
    int tg2 = tmap(k, tile, i);
    bs_ws[(bkL + tg2) * NN + n] = xd[(RR + n) * 65 + i];
    cs_ws[(bkL + tg2) * NN + n] = xd[(RR + NN + n) * 65 + i];
  }

  // ---- y -> u transpose in 64-channel chunks through xs
  const float* yb = y + (size_t)b * DD * LL;
  __syncthreads();
  for (int ch = 0; ch < 3; ++ch) {
    for (int r = ds4; r < 64; r += 4)
      xs[r * 65 + ti] = yb[(size_t)(ch * 64 + r) * LL + m];
    __syncthreads();
    float* udst = u_ws + (bkL + tg) * DD + ch * 64 + wv * 16;
#pragma unroll
    for (int j0 = 0; j0 < 16; j0 += 4) {
      float4 v;
      float* vp = (float*)&v;
#pragma unroll
      for (int q = 0; q < 4; ++q)
        vp[q] = xs[(wv * 16 + j0 + q) * 65 + ti];
      *(float4*)(udst + j0) = v;
    }
    __syncthreads();
  }
}

// ---------------- K2: pass 1 — per-chunk (P, s) ----------------
__global__ __launch_bounds__(192) void k_scan1(
    const float* __restrict__ delta_ws, const float* __restrict__ u_ws,
    const float* __restrict__ bs_ws, const float* __restrict__ A_logs,
    float* __restrict__ cP, float* __restrict__ cS)
{
  __shared__ float Bl[CL * NN];
  const int bid = blockIdx.x;
  const int c = bid & (NC - 1);
  const int bk = bid >> 6;
  const int k = bk & 3;
  const int d = threadIdx.x;
  if (c == NC - 1) return;  // last chunk's state is never consumed
  const int t0 = c * CL;

  float A2[NN];
  const float* al = A_logs + (size_t)(k * DD + d) * NN;
#pragma unroll
  for (int n = 0; n < NN; ++n) A2[n] = -__expf(al[n]) * 1.4426950408889634f;

  const float* bsrc = bs_ws + ((size_t)bk * LL + t0) * NN;
  for (int i = threadIdx.x; i < CL * NN; i += 192) Bl[i] = bsrc[i];
  __syncthreads();

  const float* dptr = delta_ws + ((size_t)bk * LL + t0) * DD + d;
  const float* uptr = u_ws + ((size_t)bk * LL + t0) * DD + d;
  float h[NN];
#pragma unroll
  for (int n = 0; n < NN; ++n) h[n] = 0.f;
  float dsum = 0.f;
  // depth-2 register prefetch pipeline (overruns stay inside ws)
  float de0 = dptr[0], uu0 = uptr[0];
  float de1 = dptr[DD], uu1 = uptr[DD];
#pragma unroll 2
  for (int t = 0; t < CL; ++t) {
    float de2 = dptr[(t + 2) * DD];
    float uu2 = uptr[(t + 2) * DD];
    float du = de0 * uu0;
    dsum += de0;
    const float4* bq = (const float4*)(Bl + t * NN);
    float4 b0 = bq[0], b1 = bq[1], b2 = bq[2], b3 = bq[3];
    const float bb[16] = {b0.x,b0.y,b0.z,b0.w, b1.x,b1.y,b1.z,b1.w,
                          b2.x,b2.y,b2.z,b2.w, b3.x,b3.y,b3.z,b3.w};
#pragma unroll
    for (int n = 0; n < NN; ++n)
      h[n] = fmaf(ex2(de0 * A2[n]), h[n], du * bb[n]);
    de0 = de1; uu0 = uu1; de1 = de2; uu1 = uu2;
  }
  float* pp = cP + (((size_t)bk * NC + c) * DD + d) * NN;
  float* sp = cS + (((size_t)bk * NC + c) * DD + d) * NN;
#pragma unroll
  for (int n = 0; n < NN; ++n) { pp[n] = ex2(dsum * A2[n]); sp[n] = h[n]; }
}

// ---------------- K2.5: prefix over chunks (in place over cP) ----------------
// h_in for chunk c (c>=1) ends up at cP slot c-1. Each element owned by one thread.
__global__ __launch_bounds__(256) void k_prefix(
    float* __restrict__ cP, const float* __restrict__ cS)
{
  const int tidg = blockIdx.x * 256 + threadIdx.x;   // 0..49151
  const int bk = tidg / (DD * NN);
  const int e = tidg - bk * (DD * NN);
  const size_t base = (size_t)bk * NC * DD * NN + e;
  const int STRIDE = DD * NN;   // 3072
  float h = 0.f;
  int c = 0;
  for (; c + 4 <= 63; c += 4) {
    float p0 = cP[base + (size_t)(c + 0) * STRIDE];
    float p1 = cP[base + (size_t)(c + 1) * STRIDE];
    float p2 = cP[base + (size_t)(c + 2) * STRIDE];
    float p3 = cP[base + (size_t)(c + 3) * STRIDE];
    float s0 = cS[base + (size_t)(c + 0) * STRIDE];
    float s1 = cS[base + (size_t)(c + 1) * STRIDE];
    float s2 = cS[base + (size_t)(c + 2) * STRIDE];
    float s3 = cS[base + (size_t)(c + 3) * STRIDE];
    h = fmaf(p0, h, s0); cP[base + (size_t)(c + 0) * STRIDE] = h;
    h = fmaf(p1, h, s1); cP[base + (size_t)(c + 1) * STRIDE] = h;
    h = fmaf(p2, h, s2); cP[base + (size_t)(c + 2) * STRIDE] = h;
    h = fmaf(p3, h, s3); cP[base + (size_t)(c + 3) * STRIDE] = h;
  }
  for (; c < 63; ++c) {
    float p = cP[base + (size_t)c * STRIDE];
    float s = cS[base + (size_t)c * STRIDE];
    h = fmaf(p, h, s);
    cP[base + (size_t)c * STRIDE] = h;
  }
}

// ---------------- K3: pass 2 — load h_in, rescan with y ----------------
__global__ __launch_bounds__(192) void k_scan2(
    float* __restrict__ dy_ws,   // delta in, y out (in-place)
    const float* __restrict__ u_ws,
    const float* __restrict__ bs_ws, const float* __restrict__ cs_ws,
    const float* __restrict__ A_logs, const float* __restrict__ Ds,
    const float* __restrict__ cHin)
{
  __shared__ float Bl[CL * NN];
  __shared__ float Cl2[CL * NN];
  const int bid = blockIdx.x;
  const int c = bid & (NC - 1);
  const int bk = bid >> 6;
  const int k = bk & 3;
  const int d = threadIdx.x;
  const int t0 = c * CL;

  float A2[NN];
  const float* al = A_logs + (size_t)(k * DD + d) * NN;
#pragma unroll
  for (int n = 0; n < NN; ++n) A2[n] = -__expf(al[n]) * 1.4426950408889634f;
  const float Dkd = Ds[k * DD + d];

  float h[NN];
  if (c == 0) {
#pragma unroll
    for (int n = 0; n < NN; ++n) h[n] = 0.f;
  } else {
    const float4* hq = (const float4*)(cHin + (((size_t)bk * NC + (c - 1)) * DD + d) * NN);
    float4 h0 = hq[0], h1 = hq[1], h2 = hq[2], h3 = hq[3];
    h[0]=h0.x; h[1]=h0.y; h[2]=h0.z; h[3]=h0.w;
    h[4]=h1.x; h[5]=h1.y; h[6]=h1.z; h[7]=h1.w;
    h[8]=h2.x; h[9]=h2.y; h[10]=h2.z; h[11]=h2.w;
    h[12]=h3.x; h[13]=h3.y; h[14]=h3.z; h[15]=h3.w;
  }

  const float* bsrc = bs_ws + ((size_t)bk * LL + t0) * NN;
  const float* csrc = cs_ws + ((size_t)bk * LL + t0) * NN;
  for (int i = threadIdx.x; i < CL * NN; i += 192) {
    Bl[i] = bsrc[i];
    Cl2[i] = csrc[i];
  }
  __syncthreads();

  float* dyp = dy_ws + ((size_t)bk * LL + t0) * DD + d;
  const float* uptr = u_ws + ((size_t)bk * LL + t0) * DD + d;
  float de0 = dyp[0], uu0 = uptr[0];
  float de1 = dyp[DD], uu1 = uptr[DD];
#pragma unroll 2
  for (int t = 0; t < CL; ++t) {
    float de2 = dyp[(t + 2) * DD];
    float uu2 = uptr[(t + 2) * DD];
    float du = de0 * uu0;
    const float4* bq = (const float4*)(Bl + t * NN);
    const float4* cq = (const float4*)(Cl2 + t * NN);
    float4 b0 = bq[0], b1 = bq[1], b2 = bq[2], b3 = bq[3];
    float4 c0 = cq[0], c1 = cq[1], c2 = cq[2], c3 = cq[3];
    const float bb[16] = {b0.x,b0.y,b0.z,b0.w, b1.x,b1.y,b1.z,b1.w,
                          b2.x,b2.y,b2.z,b2.w, b3.x,b3.y,b3.z,b3.w};
    const float cc[16] = {c0.x,c0.y,c0.z,c0.w, c1.x,c1.y,c1.z,c1.w,
                          c2.x,c2.y,c2.z,c2.w, c3.x,c3.y,c3.z,c3.w};
    float yv = 0.f;
#pragma unroll
    for (int n = 0; n < NN; ++n) {
      h[n] = fmaf(ex2(de0 * A2[n]), h[n], du * bb[n]);
      yv = fmaf(h[n], cc[n], yv);
    }
    dyp[t * DD] = fmaf(Dkd, uu0, yv);  // + Ds*u fused, overwrite delta slot
    de0 = de1; uu0 = uu1; de1 = de2; uu1 = uu2;
  }
}

// ---------------- K4: direction merge + LayerNorm ----------------
__global__ __launch_bounds__(256) void k_comb(
    const float* __restrict__ ybuf, const float* __restrict__ gamma,
    const float* __restrict__ beta, float* __restrict__ out)
{
  const int lane = threadIdx.x & 63;
  const int gl = blockIdx.x * 4 + (threadIdx.x >> 6);  // 0..B*L-1
  const int b = gl >> 12;
  const int l = gl & 4095;
  const int hh = l >> 6, ww = l & 63;
  const int lt = ww * 64 + hh;
  const size_t base = (size_t)b * KK * LL * DD;
  const float* y0 = ybuf + base + (size_t)(0 * LL + l) * DD;
  const float* y1 = ybuf + base + (size_t)(1 * LL + lt) * DD;
  const float* y2 = ybuf + base + (size_t)(2 * LL + (4095 - l)) * DD;
  const float* y3 = ybuf + base + (size_t)(3 * LL + (4095 - lt)) * DD;

  float s[3];
  float sum = 0.f, sq = 0.f;
#pragma unroll
  for (int j = 0; j < 3; ++j) {
    int d = lane + j * 64;
    float v = y0[d] + y1[d] + y2[d] + y3[d];
    s[j] = v; sum += v; sq = fmaf(v, v, sq);
  }
#pragma unroll
  for (int o = 1; o < 64; o <<= 1) {
    sum += __shfl_xor(sum, o, 64);
    sq  += __shfl_xor(sq, o, 64);
  }
  const float mu = sum * (1.f / 192.f);
  const float var = sq * (1.f / 192.f) - mu * mu;
  const float inv = rsqrtf(var + 1e-5f);
  float* op = out + (size_t)gl * DD;
#pragma unroll
  for (int j = 0; j < 3; ++j) {
    int d = lane + j * 64;
    op[d] = (s[j] - mu) * inv * gamma[d] + beta[d];
  }
}

extern "C" void kernel_launch(void* const* d_in, const int* in_sizes, int n_in,
                              void* d_out, int out_size, void* d_ws, size_t ws_size,
                              hipStream_t stream) {
  const float* x     = (const float*)d_in[0];
  const float* y     = (const float*)d_in[1];
  const float* xpw   = (const float*)d_in[2];
  const float* dpw   = (const float*)d_in[3];
  const float* dpb   = (const float*)d_in[4];
  const float* alogs = (const float*)d_in[5];
  const float* ds    = (const float*)d_in[6];
  const float* gamma = (const float*)d_in[7];
  const float* beta  = (const float*)d_in[8];
  float* w = (float*)d_ws;

  float* delta = w;                  // 12,582,912 floats (also y_out, also K4 input)
  float* u     = w + 12582912;       // 12,582,912
  float* bs    = w + 25165824;       //  1,048,576
  float* cs    = w + 26214400;       //  1,048,576
  float* cP    = w + 27262976;       //  3,145,728 (becomes h_in after k_prefix)
  float* cS    = w + 30408704;       //  3,145,728  -> total 33,554,432 floats = 128 MiB

  k_proj<<<1024, 256, 0, stream>>>(x, y, xpw, dpw, dpb, delta, u, bs, cs);
  k_scan1<<<1024, 192, 0, stream>>>(delta, u, bs, alogs, cP, cS);
  k_prefix<<<192, 256, 0, stream>>>(cP, cS);
  k_scan2<<<1024, 192, 0, stream>>>(delta, u, bs, cs, alogs, ds, cP);
  k_comb<<<4096, 256, 0, stream>>>(delta, gamma, beta, (float*)d_out);
}